// Round 1
// baseline (263.531 us; speedup 1.0000x reference)
//
#include <hip/hip_runtime.h>

#define B_  4
#define C1  256
#define C2  128
#define HH  64
#define WW  64
#define H2  128
#define W2  128

using short8  = __attribute__((ext_vector_type(8))) short;
using floatx4 = __attribute__((ext_vector_type(4))) float;
typedef unsigned short ushort_t;

#define GLOBAL_AS __attribute__((address_space(1)))
#define LDS_AS    __attribute__((address_space(3)))

// ---- workspace layout (bytes) ----
#define W1C_OFF 0u                                   // [cls4][tap4][co128][ci256] bf16
#define W1C_ELEMS (4 * 4 * 128 * 256)
#define W2C_OFF (W1C_ELEMS * 2u)                     // [tap9][o128][ci128] bf16
#define W2C_ELEMS (9 * 128 * 128)
#define KG_OFF  (W2C_OFF + W2C_ELEMS * 2u)           // [b][h][tap9][w128] fp32
#define KG_ELEMS (B_ * H2 * 9 * W2)
#define XT_OFF  (KG_OFF + KG_ELEMS * 4u)             // x -> [b][ih][iw][ci] bf16
#define XT_ELEMS (B_ * HH * WW * C1)
#define Y_OFF   (XT_OFF + XT_ELEMS * 2u)             // y -> [b][h][w][c] bf16
#define Y_ELEMS (B_ * H2 * W2 * C2)

static __device__ __forceinline__ ushort_t f2bf(float f) {
    union { float f; unsigned u; } v; v.f = f;
    unsigned r = v.u + 0x7FFFu + ((v.u >> 16) & 1u);   // RNE
    return (ushort_t)(r >> 16);
}

// ---------------------------------------------------------------------------
// Prep: w1 -> w1c[cls][tap][co][ci] bf16 (cls=p*2+pw', tap=th*2+tw)
// ---------------------------------------------------------------------------
__global__ void w1c_kernel(const float* __restrict__ w1, ushort_t* __restrict__ w1c) {
    int i = blockIdx.x * 256 + threadIdx.x;
    const int ci  = i & 255;
    const int co  = (i >> 8) & 127;
    const int tap = (i >> 15) & 3;
    const int cls = i >> 17;
    const int kh  = (cls >> 1) + 2 * (tap >> 1);
    const int kw  = (cls & 1) + 2 * (tap & 1);
    w1c[i] = f2bf(w1[((ci * C2 + co) * 4 + kh) * 4 + kw]);
}

// w2 -> w2c[tap][o][ci] bf16 with flip baked in
__global__ void w2c_kernel(const float* __restrict__ w2, ushort_t* __restrict__ w2c) {
    int i = blockIdx.x * 256 + threadIdx.x;
    const int ci  = i & 127;
    const int o   = (i >> 7) & 127;
    const int tap = i >> 14;
    const int fi  = 2 - tap / 3;
    const int fj  = 2 - tap % 3;
    w2c[i] = f2bf(w2[((ci * C2 + o) * 3 + fi) * 3 + fj]);
}

// x (NCHW fp32) -> xT[b][ih][iw][ci] bf16 via LDS transpose
__global__ __launch_bounds__(256) void xt_kernel(const float* __restrict__ x,
                                                 ushort_t* __restrict__ xT) {
    const int ih = blockIdx.x;
    const int b  = blockIdx.y;
    const int tid = threadIdx.x;
    __shared__ ushort_t tile[64 * 72];    // [iw][cc], stride 72 (16B-aligned rows)

    for (int chunk = 0; chunk < 4; ++chunk) {
        const int ci0 = chunk * 64;
        if (chunk) __syncthreads();
#pragma unroll
        for (int it = 0; it < 16; ++it) {
            const int cc = it * 4 + (tid >> 6);
            const int iw = tid & 63;
            const float v = x[(((size_t)b * C1 + ci0 + cc) * HH + ih) * WW + iw];
            tile[iw * 72 + cc] = f2bf(v);
        }
        __syncthreads();
#pragma unroll
        for (int it = 0; it < 2; ++it) {
            const int i  = it * 256 + tid;
            const int iw = i >> 3;
            const int t  = i & 7;
            const int4 v = *reinterpret_cast<const int4*>(&tile[iw * 72 + t * 8]);
            *reinterpret_cast<int4*>(&xT[(((size_t)(b * HH + ih) * WW) + iw) * C1 + ci0 + t * 8]) = v;
        }
    }
}

// ---------------------------------------------------------------------------
// k-kernel: kg[b][h][tap][w], 512 threads = 4 c-quarters x 128 w, LDS-reduced.
// ---------------------------------------------------------------------------
__global__ __launch_bounds__(512) void k_kernel(const float* __restrict__ guide,
                                                float* __restrict__ kg) {
    const int h = blockIdx.x;
    const int b = blockIdx.y;
    const int tid = threadIdx.x;
    const int cq  = tid >> 7;
    const int n   = tid & 127;

    float acc[9];
#pragma unroll
    for (int t = 0; t < 9; ++t) acc[t] = 0.f;

    const float* gb = guide + (size_t)b * C2 * H2 * W2;
    for (int c = cq * 32; c < cq * 32 + 32; ++c) {
        const float* grow = gb + (c * H2 + h) * W2;
        const float gc = grow[n];
#pragma unroll
        for (int di = 0; di < 3; ++di) {
            const int hh = h + di - 1;
            const bool rv = (hh >= 0) && (hh < H2);
            const float* gr = gb + (c * H2 + (rv ? hh : 0)) * W2;
#pragma unroll
            for (int dj = 0; dj < 3; ++dj) {
                const int col = n + dj - 1;
                const bool cv = rv && (col >= 0) && (col < W2);
                const float gn = cv ? gr[col] : 0.f;
                const float d = gn - gc;
                acc[di * 3 + dj] += d * d;
            }
        }
    }

    __shared__ float part[4][9][128];
#pragma unroll
    for (int t = 0; t < 9; ++t) part[cq][t][n] = acc[t];
    __syncthreads();

    for (int i = tid; i < 1152; i += 512) {
        const int t  = i >> 7;
        const int nn = i & 127;
        const float s = part[0][t][nn] + part[1][t][nn] + part[2][t][nn] + part[3][t][nn];
        kg[(size_t)(b * H2 + h) * 1152 + i] = __expf(-0.5f * s);
    }
}

// ---------------------------------------------------------------------------
// Deconv MFMA v3: tile 128co x 128pix, K=256 in 4 chunks of 64, 4 taps.
// A = w1c rows loaded DIRECT from global (L2-resident). B = xT halo slab
// [3 ih][66 iw][64 ci] staged ONCE per kc, shared by all 4 taps, XOR-swizzled
// 16B chunks (conflict-free ds_read_b128). Barriers: 2/kc instead of 2/(kc,tap).
// ---------------------------------------------------------------------------
__global__ __launch_bounds__(256, 2) void deconv_mfma(const ushort_t* __restrict__ xT,
                                                      const ushort_t* __restrict__ w1c,
                                                      const float* __restrict__ b1,
                                                      ushort_t* __restrict__ y) {
    const int pwc = blockIdx.x;
    const int pr  = blockIdx.y;
    const int b   = blockIdx.z;
    const int base_oh = (pr >> 1) * 4 + (pr & 1);
    const int p    = (base_oh + 1) & 1;
    const int ihA0 = (base_oh + 1 - p) >> 1;
    const int pwp  = 1 - pwc;
    const int cls  = p * 2 + pwp;

    const int tid  = threadIdx.x;
    const int lane = tid & 63;
    const int wave = tid >> 6;
    const int wm   = (wave & 1) * 64;
    const int wn   = (wave >> 1) * 64;
    const int quad = lane >> 4;
    const int l15  = lane & 15;

    // slab: 198 pixels x 64 ci = 12672 ushorts; epilogue Ot: 128 x 136 = 17408
    __shared__ __align__(16) ushort_t lds[128 * 136];

    floatx4 acc[4][4];
#pragma unroll
    for (int mi = 0; mi < 4; ++mi)
#pragma unroll
        for (int ni = 0; ni < 4; ++ni) acc[mi][ni] = (floatx4)0.f;

    const int ihbase = ihA0 - 1;
    const int iwbase = pwc - 1;

    for (int kc = 0; kc < 4; ++kc) {
        __syncthreads();                  // prior slab readers done
        // ---- stage halo slab: 198 pixels x 8 chunks = 1584 int4, zero OOB
#pragma unroll
        for (int it = 0; it < 7; ++it) {
            const int i = it * 256 + tid;
            if (i < 1584) {
                const int pix  = i >> 3;
                const int c    = i & 7;
                const int prow = pix / 66;
                const int pcol = pix - prow * 66;
                const int ih = ihbase + prow;
                const int iw = iwbase + pcol;
                int4 v = make_int4(0, 0, 0, 0);
                if (ih >= 0 && ih < HH && iw >= 0 && iw < WW)
                    v = *reinterpret_cast<const int4*>(
                        &xT[(((size_t)(b * HH + ih) * WW) + iw) * C1 + kc * 64
                            + ((c ^ (pcol & 7)) << 3)]);
                *reinterpret_cast<int4*>(&lds[pix * 64 + (c << 3)]) = v;
            }
        }
        __syncthreads();
#pragma unroll
        for (int tap = 0; tap < 4; ++tap) {
            const int th = tap >> 1, tw = tap & 1;
#pragma unroll
            for (int k2 = 0; k2 < 2; ++k2) {
                short8 af[4], bfr[4];
#pragma unroll
                for (int mi = 0; mi < 4; ++mi)
                    af[mi] = *reinterpret_cast<const short8*>(
                        &w1c[((size_t)(cls * 4 + tap) * 128 + wm + mi * 16 + l15) * 256
                             + kc * 64 + k2 * 32 + quad * 8]);
#pragma unroll
                for (int ni = 0; ni < 4; ++ni) {
                    const int n   = wn + ni * 16 + l15;
                    const int prw = (n >> 6) - th + 1;
                    const int pcl = (n & 63) + 1 - tw;
                    bfr[ni] = *reinterpret_cast<const short8*>(
                        &lds[(prw * 66 + pcl) * 64 + (((k2 * 4 + quad) ^ (pcl & 7)) << 3)]);
                }
#pragma unroll
                for (int mi = 0; mi < 4; ++mi)
#pragma unroll
                    for (int ni = 0; ni < 4; ++ni)
                        acc[mi][ni] = __builtin_amdgcn_mfma_f32_16x16x32_bf16(
                            af[mi], bfr[ni], acc[mi][ni], 0, 0, 0);
            }
        }
    }

    // ---- epilogue: transpose in LDS -> y[b][oh][ow][co] bf16
    __syncthreads();
    ushort_t* Ot = lds;                      // [n 0..127][co 0..127], stride 136
#pragma unroll
    for (int mi = 0; mi < 4; ++mi)
#pragma unroll
        for (int ni = 0; ni < 4; ++ni) {
            const int n = wn + ni * 16 + l15;
#pragma unroll
            for (int r = 0; r < 4; ++r) {
                const int co = wm + mi * 16 + quad * 4 + r;
                Ot[n * 136 + co] = f2bf(acc[mi][ni][r] + b1[co]);
            }
        }
    __syncthreads();
#pragma unroll
    for (int it = 0; it < 8; ++it) {
        const int i   = it * 256 + tid;
        const int n   = i >> 4;
        const int t   = i & 15;
        const int rh  = n >> 6;
        const int n64 = n & 63;
        const int oh  = base_oh + 2 * rh;
        const int ow  = 2 * n64 + pwc;
        const int4 v = *reinterpret_cast<const int4*>(&Ot[n * 136 + t * 8]);
        *reinterpret_cast<int4*>(&y[(((size_t)(b * H2 + oh) * W2) + ow) * C2 + t * 8]) = v;
    }
}

// ---------------------------------------------------------------------------
// PAC MFMA v3: tile 128o x 128w per (b,h).
//  - A-fragments loaded DIRECT from global w2c (L2-resident) -> no A-stage.
//  - Y slab double-buffered in LDS via global_load_lds(16B): linear dest,
//    inverse-XOR-swizzled source, XOR-swizzled ds_read (G21). Stride 128
//    elements + chunk^=(row&7) -> conflict-free ds_read_b128.
//  - ONE __syncthreads per di (3/block); next slab streams under compute.
//  - Grid flattened to 512 with XCD swizzle: each XCD owns 64 consecutive h.
// ---------------------------------------------------------------------------
__global__ __launch_bounds__(256, 2) void pac_mfma(const ushort_t* __restrict__ y,
                                                   const float* __restrict__ kg,
                                                   const ushort_t* __restrict__ w2c,
                                                   const float* __restrict__ b2,
                                                   float* __restrict__ out) {
    const int bid = blockIdx.x;
    const int swz = ((bid & 7) << 6) + (bid >> 3);   // XCD-contiguous h ranges
    const int h = swz & 127;
    const int b = swz >> 7;

    const int tid  = threadIdx.x;
    const int lane = tid & 63;
    const int wave = tid >> 6;
    const int wm   = (wave & 1) * 64;
    const int wn   = (wave >> 1) * 64;
    const int quad = lane >> 4;
    const int l15  = lane & 15;

    __shared__ __align__(16) ushort_t Ylds[2][130 * 128];  // rows: w+1 (0,129 = zero halo)
    __shared__ float k_lds[9 * 128];

    // zero halo rows of both buffers (rows 0 and 129)
    {
        const int zb = tid >> 7, zr = (tid >> 6) & 1, zw = tid & 63;
        *reinterpret_cast<int*>(&Ylds[zb][(zr ? 129 : 0) * 128 + zw * 2]) = 0;
    }
    for (int i = tid; i < 1152; i += 256)
        k_lds[i] = kg[(size_t)(b * H2 + h) * 1152 + i];

    const int dlo = (h == 0) ? 1 : 0;
    const int dhi = (h == H2 - 1) ? 1 : 2;

    // ---- prologue: stage first slab into buffer 0 (async, drained by barrier)
    {
        const ushort_t* ysrc = y + (size_t)(b * H2 + (h + dlo - 1)) * W2 * C2;
        ushort_t* dst = &Ylds[0][128];                 // row 1
#pragma unroll
        for (int it = 0; it < 8; ++it) {
            const int i = it * 256 + tid;
            const int r = i >> 4;
            const int c = i & 15;
            const ushort_t* src = ysrc + r * C2 + ((c ^ ((r + 1) & 7)) << 3);
            __builtin_amdgcn_global_load_lds((const GLOBAL_AS void*)src,
                                             (LDS_AS void*)(dst + i * 8), 16, 0, 0);
        }
    }
    __syncthreads();

    float out_acc[4][4][4];
#pragma unroll
    for (int mi = 0; mi < 4; ++mi)
#pragma unroll
        for (int ni = 0; ni < 4; ++ni)
#pragma unroll
            for (int r = 0; r < 4; ++r) out_acc[mi][ni][r] = 0.f;

    int cur = 0;
    for (int di = dlo; di <= dhi; ++di) {
        // ---- stream next slab into the other buffer (no barrier needed: WAR
        // on buf^1 was resolved by the previous __syncthreads)
        if (di < dhi) {
            const ushort_t* ysrc = y + (size_t)(b * H2 + (h + di)) * W2 * C2;
            ushort_t* dst = &Ylds[cur ^ 1][128];
#pragma unroll
            for (int it = 0; it < 8; ++it) {
                const int i = it * 256 + tid;
                const int r = i >> 4;
                const int c = i & 15;
                const ushort_t* src = ysrc + r * C2 + ((c ^ ((r + 1) & 7)) << 3);
                __builtin_amdgcn_global_load_lds((const GLOBAL_AS void*)src,
                                                 (LDS_AS void*)(dst + i * 8), 16, 0, 0);
            }
        }
        const ushort_t* Yc = Ylds[cur];
#pragma unroll
        for (int dj = 0; dj < 3; ++dj) {
            const int tap = di * 3 + dj;
            floatx4 acc[4][4];
#pragma unroll
            for (int mi = 0; mi < 4; ++mi)
#pragma unroll
                for (int ni = 0; ni < 4; ++ni) acc[mi][ni] = (floatx4)0.f;

#pragma unroll
            for (int kc = 0; kc < 4; ++kc) {
                short8 af[4], bfr[4];
#pragma unroll
                for (int mi = 0; mi < 4; ++mi)
                    af[mi] = *reinterpret_cast<const short8*>(
                        &w2c[((size_t)(tap * 128 + wm + mi * 16 + l15)) * 128
                             + kc * 32 + quad * 8]);
#pragma unroll
                for (int ni = 0; ni < 4; ++ni) {
                    const int R = wn + ni * 16 + l15 + dj;
                    bfr[ni] = *reinterpret_cast<const short8*>(
                        &Yc[R * 128 + (((kc * 4 + quad) ^ (R & 7)) << 3)]);
                }
#pragma unroll
                for (int mi = 0; mi < 4; ++mi)
#pragma unroll
                    for (int ni = 0; ni < 4; ++ni)
                        acc[mi][ni] = __builtin_amdgcn_mfma_f32_16x16x32_bf16(
                            af[mi], bfr[ni], acc[mi][ni], 0, 0, 0);
            }
            // ---- scale by k_tap[w] and accumulate
            float kv[4];
#pragma unroll
            for (int ni = 0; ni < 4; ++ni)
                kv[ni] = k_lds[tap * 128 + wn + ni * 16 + l15];
#pragma unroll
            for (int mi = 0; mi < 4; ++mi)
#pragma unroll
                for (int ni = 0; ni < 4; ++ni)
#pragma unroll
                    for (int r = 0; r < 4; ++r)
                        out_acc[mi][ni][r] += kv[ni] * acc[mi][ni][r];
        }
        __syncthreads();   // drains global_load_lds (vmcnt) + LDS; swap buffers
        cur ^= 1;
    }

    // ---- final store: out NCHW fp32
#pragma unroll
    for (int mi = 0; mi < 4; ++mi)
#pragma unroll
        for (int ni = 0; ni < 4; ++ni) {
            const int w = wn + ni * 16 + l15;
#pragma unroll
            for (int r = 0; r < 4; ++r) {
                const int o = wm + mi * 16 + quad * 4 + r;
                out[(((size_t)b * C2 + o) * H2 + h) * W2 + w] = out_acc[mi][ni][r] + b2[o];
            }
        }
}

extern "C" void kernel_launch(void* const* d_in, const int* in_sizes, int n_in,
                              void* d_out, int out_size, void* d_ws, size_t ws_size,
                              hipStream_t stream) {
    const float* x     = (const float*)d_in[0];
    const float* guide = (const float*)d_in[1];
    const float* w1    = (const float*)d_in[2];
    const float* b1    = (const float*)d_in[3];
    const float* w2    = (const float*)d_in[4];
    const float* b2    = (const float*)d_in[5];
    float* out = (float*)d_out;

    ushort_t* w1c = (ushort_t*)((char*)d_ws + W1C_OFF);
    ushort_t* w2c = (ushort_t*)((char*)d_ws + W2C_OFF);
    float*    kg  = (float*)((char*)d_ws + KG_OFF);
    ushort_t* xT  = (ushort_t*)((char*)d_ws + XT_OFF);
    ushort_t* y   = (ushort_t*)((char*)d_ws + Y_OFF);

    w1c_kernel<<<W1C_ELEMS / 256, 256, 0, stream>>>(w1, w1c);
    w2c_kernel<<<W2C_ELEMS / 256, 256, 0, stream>>>(w2, w2c);
    xt_kernel<<<dim3(HH, B_), 256, 0, stream>>>(x, xT);
    k_kernel<<<dim3(H2, B_), 512, 0, stream>>>(guide, kg);
    deconv_mfma<<<dim3(2, 64, B_), 256, 0, stream>>>(xT, w1c, b1, y);
    pac_mfma<<<512, 256, 0, stream>>>(y, kg, w2c, b2, out);
}